// Round 1
// baseline (215.406 us; speedup 1.0000x reference)
//
#include <hip/hip_runtime.h>
#include <hip/hip_bf16.h>

#define BB 4
#define SS 2048
#define DIN 512
#define UU 64
#define WINR 32
#define LTOT 132064   // sum of per-anchor window lengths
#define GQ 16         // queries per attn block (16 waves x 1 query)
#define VST 200       // padded key-dim stride (ushorts/floats): 40 left-pad + 144 band + right pad
                      // 400 B rows -> lane word-offset 100 -> 4*l mod 32 -> even 8-way b128 reads

typedef __attribute__((ext_vector_type(8))) short short8;
typedef __attribute__((ext_vector_type(4))) float float4v;
typedef __attribute__((ext_vector_type(4))) uint uint4v;

static __device__ __forceinline__ ushort f2bf(float f) {
    union { __hip_bfloat16 h; ushort u; } c;
    c.h = __float2bfloat16(f);
    return c.u;
}
static __device__ __forceinline__ float bf2f(ushort u) {
    union { float f; uint v; } c;
    c.v = ((uint)u) << 16;
    return c.f;
}
static __device__ __forceinline__ float bfbits(uint u) {   // float from raw bits
    union { float f; uint v; } c;
    c.v = u;
    return c.f;
}

// offsets[s] = sum_{t<s} (min(t+33,S) - max(t-32,0)), closed form (verified vs cumsum)
__device__ __forceinline__ int offs_of(int s) {
    int a = s < (SS - 33) ? s : (SS - 33);
    int m = (s - 33) > 0 ? (s - 33) : 0;
    return a * (a - 1) / 2 + 33 * a + (s - a) * SS - m * (m + 1) / 2;
}

// ---------------- Kernel 0: W (fp32, K-major [512][64]) -> Wt (bf16, N-major [3][64][512]) ----
__global__ __launch_bounds__(256) void prep_w(
    const float* __restrict__ Wq, const float* __restrict__ Wk, const float* __restrict__ Wv,
    ushort* __restrict__ Wt)
{
    __shared__ float T[64][65];
    const int mtx = blockIdx.x >> 3;   // 0..2
    const int kc  = blockIdx.x & 7;    // 0..7  (K chunk of 64)
    const float* W = (mtx == 0) ? Wq : ((mtx == 1) ? Wk : Wv);
    const int tid = threadIdx.x;
    for (int idx = tid; idx < 64 * 64; idx += 256) {
        const int k = idx >> 6, n = idx & 63;          // coalesced read over n
        T[n][k] = W[(size_t)(kc * 64 + k) * UU + n];
    }
    __syncthreads();
    for (int idx = tid; idx < 64 * 64; idx += 256) {
        const int n = idx >> 6, kl = idx & 63;
        Wt[(size_t)mtx * UU * DIN + (size_t)n * DIN + kc * 64 + kl] = f2bf(T[n][kl]);
    }
}

// ---------------- Kernel 1: QKV projection, MFMA 16x16x32, K-split across 4 waves ----------
// (verbatim, known-pass) grid = 3*512 blocks x 256 threads.
__global__ __launch_bounds__(256) void qkv_mfma(
    const float* __restrict__ query, const float* __restrict__ value,
    const ushort* __restrict__ Wt,
    const float* __restrict__ bq, const float* __restrict__ bk, const float* __restrict__ bv,
    float* __restrict__ Qs, ushort* __restrict__ Kf, ushort* __restrict__ Vf)
{
    __shared__ float red[4][16 * UU];   // 16 KB partials
    const int bid = blockIdx.x;
    const int mtx = bid >> 9;           // 0=Q 1=K 2=V
    const int rt  = bid & 511;
    const int tid = threadIdx.x;
    const int kq = tid >> 6;            // K-quarter
    const int lane = tid & 63;
    const int m16 = lane & 15, quad = lane >> 4;

    const float* X = (mtx == 0) ? query : value;
    const float* Xrow = X + (size_t)(rt * 16 + m16) * DIN + kq * 128 + quad * 8;
    const ushort* Wm = Wt + (size_t)mtx * UU * DIN + (size_t)m16 * DIN + kq * 128 + quad * 8;

    float4v acc[4];
#pragma unroll
    for (int nb = 0; nb < 4; ++nb) acc[nb] = (float4v){0.f, 0.f, 0.f, 0.f};

#pragma unroll
    for (int kk = 0; kk < 4; ++kk) {
        const float4 xa = *(const float4*)(Xrow + kk * 32);
        const float4 xb = *(const float4*)(Xrow + kk * 32 + 4);
        short8 a;
        a[0] = (short)f2bf(xa.x); a[1] = (short)f2bf(xa.y);
        a[2] = (short)f2bf(xa.z); a[3] = (short)f2bf(xa.w);
        a[4] = (short)f2bf(xb.x); a[5] = (short)f2bf(xb.y);
        a[6] = (short)f2bf(xb.z); a[7] = (short)f2bf(xb.w);
#pragma unroll
        for (int nb = 0; nb < 4; ++nb) {
            const short8 bfr = *(const short8*)(Wm + (size_t)nb * 16 * DIN + kk * 32);
            acc[nb] = __builtin_amdgcn_mfma_f32_16x16x32_bf16(a, bfr, acc[nb], 0, 0, 0);
        }
    }

    // C layout (16x16x32): col = lane&15 (within nb tile), row = quad*4 + reg
#pragma unroll
    for (int nb = 0; nb < 4; ++nb)
#pragma unroll
        for (int reg = 0; reg < 4; ++reg)
            red[kq][(quad * 4 + reg) * UU + nb * 16 + m16] = acc[nb][reg];
    __syncthreads();

    const float* bias = (mtx == 0) ? bq : ((mtx == 1) ? bk : bv);
#pragma unroll
    for (int i = 0; i < 4; ++i) {
        const int e = tid + 256 * i;
        const int col = e & 63, row = e >> 6;
        float s = red[0][e] + red[1][e] + red[2][e] + red[3][e] + bias[col];
        const size_t gi = (size_t)(rt * 16 + row) * UU + col;
        if (mtx == 0)      Qs[gi] = s * 0.125f;    // 1/sqrt(UNITS)
        else if (mtx == 1) Kf[gi] = f2bf(s);
        else               Vf[gi] = f2bf(s);
    }
}

// ---------------- Kernel 2: banded exp-scores + sliding-window weighted sums (v2) ----------
// 512 blocks x 1024 thr (16 waves); wave w = query q0+w.
// All LDS traffic restructured to 16B granularity:
//   - K is NOT staged (L2-resident, 1 MB): dot reads global dwordx4 directly.
//   - q read via scalar loads (readfirstlane-uniform pointer -> s_load, SGPR fmac operands).
//   - V stored TRANSPOSED Vt[d][jp], stride VST=200 ushorts (400 B rows, even 8-way banks),
//     so lane d fetches 8 keys per ds_read_b128.
//   - exp scores masked to 0 outside each query's own +-64 band; arrays left-padded by 40
//     zeroed columns => "virtual anchor" sliding: start a few anchors early (store-masked)
//     so the add stream is 8-aligned; removes sit at a constant phase-7 offset handled by
//     one rolling scalar. Init is always exactly 9 aligned b128 batches; anchor loop does
//     6 ds_read_b128 + 8 stores per 8 anchors. No scalar LDS loops anywhere.
// out(s) = (accA - accR) * rcp(denA - denR): A = add-prefix, R = remove-prefix.
// LDS 38.4 KB -> 2 blocks/CU x 16 waves = 32 waves/CU.
__global__ __launch_bounds__(1024) void attn_kernel(
    const float* __restrict__ Qs, const ushort* __restrict__ Kf,
    const ushort* __restrict__ Vf, float* __restrict__ out)
{
    __shared__ ushort Vt[UU * VST];      // 25,600 B  V transposed: Vt[d][jp], jp = j - j0 + 40
    __shared__ float  evf[GQ * VST];     // 12,800 B  exp-scores per query

    const int blk = blockIdx.x;
    const int b = blk >> 7;              // 128 blocks per batch
    const int q0 = (blk & 127) << 4;
    const int tid = threadIdx.x;
    const int lane = tid & 63;
    const int wq = __builtin_amdgcn_readfirstlane(tid >> 6);   // provably wave-uniform

    const int j0 = max(q0 - 2 * WINR, 0);
    const int j1 = min(q0 + GQ - 1 + 2 * WINR + 1, SS);
    const int nw = j1 - j0;

    // ---- zero Vt fully (pads must be 0.0, not garbage: 0*NaN would poison acc) + evf left pad
    for (int idx = tid; idx < UU * VST / 2; idx += 1024) ((uint*)Vt)[idx] = 0u;
    if (tid < GQ * 40) evf[(tid / 40) * VST + (tid % 40)] = 0.f;
    __syncthreads();

    // ---- stage V transposed (center columns [40, 40+nw)) ----
    const uint* Vg = (const uint*)(Vf + ((size_t)b * SS + j0) * UU);
    for (int idx = tid; idx < nw * 32; idx += 1024) {
        const int j = idx >> 5, d2 = idx & 31;
        const uint v = Vg[idx];
        Vt[(2 * d2) * VST + 40 + j]     = (ushort)v;
        Vt[(2 * d2 + 1) * VST + 40 + j] = (ushort)(v >> 16);
    }
    __syncthreads();

    // ---- phase B: e = exp(q.k) over this query's band, zero outside; K direct from global
    const int qi = q0 + wq;
    const int blo = max(qi - 2 * WINR, 0);
    const int bhi = min(qi + 2 * WINR + 1, SS);
    const float* qp = Qs + ((size_t)b * SS + qi) * UU;   // uniform -> scalar loads
#pragma unroll
    for (int pass = 0; pass < 3; ++pass) {
        const int jj = pass * 64 + lane;
        const int j = j0 + jj;
        const bool live = (jj < nw) && (j >= blo) && (j < bhi);
        const uint* kr = (const uint*)(Kf + ((size_t)b * SS + (live ? j : j0)) * UU);
        float dot = 0.f;
#pragma unroll
        for (int c = 0; c < 8; ++c) {
            const uint4v kp = *(const uint4v*)(kr + c * 4);   // global_load_dwordx4 (L2 hit)
#pragma unroll
            for (int u = 0; u < 4; ++u) {
                dot = fmaf(qp[c * 8 + 2 * u],     bfbits(kp[u] << 16),         dot);
                dot = fmaf(qp[c * 8 + 2 * u + 1], bfbits(kp[u] & 0xffff0000u), dot);
            }
        }
        const float e = live ? __expf(dot) : 0.f;
        if (jj < VST - 40) evf[wq * VST + 40 + jj] = e;   // cols [40, 200) fully written
    }
    __syncthreads();

    // ---- phase C: virtual-anchor sliding window, all b128-aligned ----
    const int s_lo = max(qi - WINR, 0);
    const int s_hi = min(qi + WINR, SS - 1);
    const int a = (s_lo - j0 - 7) & 7;        // virtual head so add-stream is 8-aligned
    const int s_start = s_lo - a;
    const int I_s = s_start - j0 + 8;         // first remove jp; == 7 (mod 8)
    const int I_f = I_s - 7;                  // aligned; init covers [I_f, I_f+72)
    const int A0 = I_f + 72;                  // aligned add-block base (= first add jp)

    const ushort* vrow = Vt + lane * VST;     // this lane's output dim d = lane
    const float*  erow = evf + wq * VST;

    float accA = 0.f, denA = 0.f, accR = 0.f, denR = 0.f;
#pragma unroll
    for (int t = 0; t < 9; ++t) {             // init window(s_start), 7 leading zeros included
        const int base = I_f + 8 * t;
        const uint4v  vv = *(const uint4v*)(vrow + base);
        const float4v e0 = *(const float4v*)(erow + base);
        const float4v e1 = *(const float4v*)(erow + base + 4);
#pragma unroll
        for (int k = 0; k < 8; ++k) {
            const float e = (k < 4) ? e0[k] : e1[k - 4];
            const uint wv = vv[k >> 1];
            const float v = (k & 1) ? bfbits(wv & 0xffff0000u) : bfbits(wv << 16);
            accA = fmaf(e, v, accA);
            denA += e;
        }
    }

    // rolling carry: element 7 of R-block (constant phase offset of the remove stream)
    float pE7 = erow[I_s];
    float pV7 = bf2f(vrow[I_s]);

    int off = offs_of(s_lo);
    float* outb = out + (size_t)b * LTOT * UU;
    const int ng = (s_hi - s_start + 8) >> 3;
    for (int g = 0; g < ng; ++g) {
        const int Ab = A0 + 8 * g;
        const uint4v  Av  = *(const uint4v*)(vrow + Ab);
        const float4v Ae0 = *(const float4v*)(erow + Ab);
        const float4v Ae1 = *(const float4v*)(erow + Ab + 4);
        const int Rb = I_f + 8 * (g + 1);
        const uint4v  Rv  = *(const uint4v*)(vrow + Rb);
        const float4v Re0 = *(const float4v*)(erow + Rb);
        const float4v Re1 = *(const float4v*)(erow + Rb + 4);
        int s = s_start + 8 * g;
#pragma unroll
        for (int k = 0; k < 8; ++k, ++s) {
            if (s >= s_lo && s <= s_hi) {     // wave-uniform predicate (virtual/tail anchors skip)
                const int st = (s - WINR > 0) ? s - WINR : 0;
                const int en = (s + WINR + 1 < SS) ? s + WINR + 1 : SS;
                const float r = __builtin_amdgcn_rcpf(denA - denR);
                outb[(size_t)(off + qi - st) * UU + lane] = (accA - accR) * r;
                off += en - st;
            }
            {   // add key s+33 (element k of A block; e=0 past band/seq-end)
                const float e = (k < 4) ? Ae0[k] : Ae1[k - 4];
                const uint wv = Av[k >> 1];
                const float v = (k & 1) ? bfbits(wv & 0xffff0000u) : bfbits(wv << 16);
                accA = fmaf(e, v, accA);
                denA += e;
            }
            {   // remove key s-32 (k==0 -> carried elem 7 of prev R block, else new block k-1)
                float e, v;
                if (k == 0) { e = pE7; v = pV7; }
                else {
                    const int m = k - 1;
                    e = (m < 4) ? Re0[m] : Re1[m - 4];
                    const uint wv = Rv[m >> 1];
                    v = (m & 1) ? bfbits(wv & 0xffff0000u) : bfbits(wv << 16);
                }
                accR = fmaf(e, v, accR);
                denR += e;
            }
        }
        pE7 = Re1[3];
        pV7 = bfbits(Rv[3] & 0xffff0000u);
    }
}

extern "C" void kernel_launch(void* const* d_in, const int* in_sizes, int n_in,
                              void* d_out, int out_size, void* d_ws, size_t ws_size,
                              hipStream_t stream) {
    const float* query = (const float*)d_in[0];
    const float* value = (const float*)d_in[1];
    const float* Wq = (const float*)d_in[2];
    const float* bq = (const float*)d_in[3];
    const float* Wk = (const float*)d_in[4];
    const float* bk = (const float*)d_in[5];
    const float* Wv = (const float*)d_in[6];
    const float* bv = (const float*)d_in[7];
    float* out = (float*)d_out;

    // ws: Qs fp32 (2 MB) + Kf bf16 (1 MB) + Vf bf16 (1 MB)
    float* Qs = (float*)d_ws;
    ushort* Kf = (ushort*)(Qs + (size_t)BB * SS * UU);
    ushort* Vf = Kf + (size_t)BB * SS * UU;
    // Wt (bf16 [3][64][512], 192 KB) in the TAIL of d_out: prep_w writes, qkv_mfma reads,
    // attn_kernel then overwrites every output row (stream-ordered, 16B-aligned).
    ushort* Wt = (ushort*)((float*)d_out + (size_t)out_size) - (size_t)3 * UU * DIN;

    prep_w<<<24, 256, 0, stream>>>(Wq, Wk, Wv, Wt);
    qkv_mfma<<<3 * 512, 256, 0, stream>>>(query, value, Wt, bq, bk, bv, Qs, Kf, Vf);
    attn_kernel<<<512, 1024, 0, stream>>>(Qs, Kf, Vf, out);
}

// Round 2
// 198.648 us; speedup vs baseline: 1.0844x; 1.0844x over previous
//
#include <hip/hip_runtime.h>
#include <hip/hip_bf16.h>

#define BB 4
#define SS 2048
#define DIN 512
#define UU 64
#define WINR 32
#define LTOT 132064   // sum of per-anchor window lengths
#define GQ 16         // queries per attn block (16 waves x 1 query)
#define VST 200       // padded key-dim stride (ushorts/floats): 40 left-pad + 144 band + 16 right pad
                      // 400 B rows -> b128-aligned at any 8-element offset

typedef __attribute__((ext_vector_type(8))) short short8;
typedef __attribute__((ext_vector_type(4))) float float4v;
typedef __attribute__((ext_vector_type(4))) uint uint4v;

static __device__ __forceinline__ ushort f2bf(float f) {
    union { __hip_bfloat16 h; ushort u; } c;
    c.h = __float2bfloat16(f);
    return c.u;
}
static __device__ __forceinline__ float bf2f(ushort u) {
    union { float f; uint v; } c;
    c.v = ((uint)u) << 16;
    return c.f;
}
static __device__ __forceinline__ float bfbits(uint u) {   // float from raw bits
    union { float f; uint v; } c;
    c.v = u;
    return c.f;
}

// offsets[s] = sum_{t<s} (min(t+33,S) - max(t-32,0)), closed form (verified vs cumsum)
__device__ __forceinline__ int offs_of(int s) {
    int a = s < (SS - 33) ? s : (SS - 33);
    int m = (s - 33) > 0 ? (s - 33) : 0;
    return a * (a - 1) / 2 + 33 * a + (s - a) * SS - m * (m + 1) / 2;
}

// ---------------- Kernel 0: W (fp32, K-major [512][64]) -> Wt (bf16, N-major [3][64][512]) ----
__global__ __launch_bounds__(256) void prep_w(
    const float* __restrict__ Wq, const float* __restrict__ Wk, const float* __restrict__ Wv,
    ushort* __restrict__ Wt)
{
    __shared__ float T[64][65];
    const int mtx = blockIdx.x >> 3;   // 0..2
    const int kc  = blockIdx.x & 7;    // 0..7  (K chunk of 64)
    const float* W = (mtx == 0) ? Wq : ((mtx == 1) ? Wk : Wv);
    const int tid = threadIdx.x;
    for (int idx = tid; idx < 64 * 64; idx += 256) {
        const int k = idx >> 6, n = idx & 63;          // coalesced read over n
        T[n][k] = W[(size_t)(kc * 64 + k) * UU + n];
    }
    __syncthreads();
    for (int idx = tid; idx < 64 * 64; idx += 256) {
        const int n = idx >> 6, kl = idx & 63;
        Wt[(size_t)mtx * UU * DIN + (size_t)n * DIN + kc * 64 + kl] = f2bf(T[n][kl]);
    }
}

// ---------------- Kernel 1: QKV projection, MFMA 16x16x32, K-split across 4 waves ----------
// (verbatim, known-pass) grid = 3*512 blocks x 256 threads.
__global__ __launch_bounds__(256) void qkv_mfma(
    const float* __restrict__ query, const float* __restrict__ value,
    const ushort* __restrict__ Wt,
    const float* __restrict__ bq, const float* __restrict__ bk, const float* __restrict__ bv,
    float* __restrict__ Qs, ushort* __restrict__ Kf, ushort* __restrict__ Vf)
{
    __shared__ float red[4][16 * UU];   // 16 KB partials
    const int bid = blockIdx.x;
    const int mtx = bid >> 9;           // 0=Q 1=K 2=V
    const int rt  = bid & 511;
    const int tid = threadIdx.x;
    const int kq = tid >> 6;            // K-quarter
    const int lane = tid & 63;
    const int m16 = lane & 15, quad = lane >> 4;

    const float* X = (mtx == 0) ? query : value;
    const float* Xrow = X + (size_t)(rt * 16 + m16) * DIN + kq * 128 + quad * 8;
    const ushort* Wm = Wt + (size_t)mtx * UU * DIN + (size_t)m16 * DIN + kq * 128 + quad * 8;

    float4v acc[4];
#pragma unroll
    for (int nb = 0; nb < 4; ++nb) acc[nb] = (float4v){0.f, 0.f, 0.f, 0.f};

#pragma unroll
    for (int kk = 0; kk < 4; ++kk) {
        const float4 xa = *(const float4*)(Xrow + kk * 32);
        const float4 xb = *(const float4*)(Xrow + kk * 32 + 4);
        short8 a;
        a[0] = (short)f2bf(xa.x); a[1] = (short)f2bf(xa.y);
        a[2] = (short)f2bf(xa.z); a[3] = (short)f2bf(xa.w);
        a[4] = (short)f2bf(xb.x); a[5] = (short)f2bf(xb.y);
        a[6] = (short)f2bf(xb.z); a[7] = (short)f2bf(xb.w);
#pragma unroll
        for (int nb = 0; nb < 4; ++nb) {
            const short8 bfr = *(const short8*)(Wm + (size_t)nb * 16 * DIN + kk * 32);
            acc[nb] = __builtin_amdgcn_mfma_f32_16x16x32_bf16(a, bfr, acc[nb], 0, 0, 0);
        }
    }

    // C layout (16x16x32): col = lane&15 (within nb tile), row = quad*4 + reg
#pragma unroll
    for (int nb = 0; nb < 4; ++nb)
#pragma unroll
        for (int reg = 0; reg < 4; ++reg)
            red[kq][(quad * 4 + reg) * UU + nb * 16 + m16] = acc[nb][reg];
    __syncthreads();

    const float* bias = (mtx == 0) ? bq : ((mtx == 1) ? bk : bv);
#pragma unroll
    for (int i = 0; i < 4; ++i) {
        const int e = tid + 256 * i;
        const int col = e & 63, row = e >> 6;
        float s = red[0][e] + red[1][e] + red[2][e] + red[3][e] + bias[col];
        const size_t gi = (size_t)(rt * 16 + row) * UU + col;
        if (mtx == 0)      Qs[gi] = s * 0.125f;    // 1/sqrt(UNITS)
        else if (mtx == 1) Kf[gi] = f2bf(s);
        else               Vf[gi] = f2bf(s);
    }
}

// ---------------- Kernel 2: MFMA scores + b128 sliding-window sums (v3) ----------
// 512 blocks x 1024 thr (16 waves); wave w = query q0+w in phase C.
// Changes vs v2 (which was neutral):
//  - __launch_bounds__(1024, 8): force VGPR<=64 so 2 blocks/CU (32 waves/CU) actually holds.
//  - Phase B is now MFMA: scores(16q x 144k) = 9 tiles of 16x16x64, one per wave (waves 0-8).
//    K fragments read direct from global Kf with qkv_mfma's fragment addressing (16 lines per
//    instr, not 64); Q split hi/lo bf16 (4 MFMAs) to preserve fp32-grade score accuracy.
//  - Waves 9-15 stage V-transposed (stride VST=200) concurrently with the score MFMAs.
//  - evf fully zeroed with b128 stores (tiles only write the 144-col band).
// Phase C (unchanged from v2): virtual-anchor sliding window, all ds_read_b128-aligned;
// out(s) = (accA - accR) * rcp(denA - denR), A = add-prefix, R = remove-prefix.
// LDS 38.4 KB -> 2 blocks/CU.
__global__ __launch_bounds__(1024, 8) void attn_kernel(
    const float* __restrict__ Qs, const ushort* __restrict__ Kf,
    const ushort* __restrict__ Vf, float* __restrict__ out)
{
    __shared__ __align__(16) ushort Vt[UU * VST];      // 25,600 B  Vt[d][jp], jp = j - j0 + 40
    __shared__ __align__(16) float  evf[GQ * VST];     // 12,800 B  exp-scores per query

    const int blk = blockIdx.x;
    const int b = blk >> 7;              // 128 blocks per batch
    const int q0 = (blk & 127) << 4;
    const int tid = threadIdx.x;
    const int lane = tid & 63;
    const int wq = __builtin_amdgcn_readfirstlane(tid >> 6);   // provably wave-uniform

    const int j0 = max(q0 - 2 * WINR, 0);
    const int j1 = min(q0 + GQ - 1 + 2 * WINR + 1, SS);
    const int nw = j1 - j0;

    // ---- zero Vt (pads must be 0.0: 0*NaN would poison acc) and all of evf, b128 stores ----
    {
        const uint4v z = (uint4v){0u, 0u, 0u, 0u};
        uint4v* V4 = (uint4v*)Vt;                      // 1600 vectors
        uint4v* E4 = (uint4v*)evf;                     //  800 vectors
        for (int i = tid; i < 1600; i += 1024) V4[i] = z;
        for (int i = tid; i < 800;  i += 1024) E4[i] = z;
    }
    __syncthreads();

    if (wq >= 9) {
        // ---- waves 9..15: stage V transposed (center columns [40, 40+nw)) ----
        const uint* Vg = (const uint*)(Vf + ((size_t)b * SS + j0) * UU);
        for (int idx = tid - 9 * 64; idx < nw * 32; idx += 7 * 64) {
            const int j = idx >> 5, d2 = idx & 31;
            const uint v = Vg[idx];
            Vt[(2 * d2) * VST + 40 + j]     = (ushort)v;
            Vt[(2 * d2 + 1) * VST + 40 + j] = (ushort)(v >> 16);
        }
    } else {
        // ---- waves 0..8: score tile t = wq -> evf rows [0,16), cols [40+16t, 40+16t+16) ----
        const int t = wq;
        const int m16 = lane & 15, quad = lane >> 4;
        const int jb = j0 + 16 * t + m16;              // this lane's key index (unclamped)
        const int jr = jb < SS ? jb : SS - 1;          // clamped for the load
        const ushort* kr = Kf + ((size_t)b * SS + jr) * UU + quad * 8;
        const float*  qr = Qs + ((size_t)b * SS + q0 + m16) * UU + quad * 8;
        const short8 kb0 = *(const short8*)(kr);         // k in [quad*8, quad*8+8)
        const short8 kb1 = *(const short8*)(kr + 32);    // k + 32
        short8 ah0, al0, ah1, al1;                       // Q hi/lo bf16 split
#pragma unroll
        for (int e = 0; e < 8; ++e) {
            const float qa = qr[e], qb = qr[e + 32];
            const ushort h0 = f2bf(qa);
            ah0[e] = (short)h0; al0[e] = (short)f2bf(qa - bf2f(h0));
            const ushort h1 = f2bf(qb);
            ah1[e] = (short)h1; al1[e] = (short)f2bf(qb - bf2f(h1));
        }
        float4v acc = (float4v){0.f, 0.f, 0.f, 0.f};
        acc = __builtin_amdgcn_mfma_f32_16x16x32_bf16(ah0, kb0, acc, 0, 0, 0);
        acc = __builtin_amdgcn_mfma_f32_16x16x32_bf16(al0, kb0, acc, 0, 0, 0);
        acc = __builtin_amdgcn_mfma_f32_16x16x32_bf16(ah1, kb1, acc, 0, 0, 0);
        acc = __builtin_amdgcn_mfma_f32_16x16x32_bf16(al1, kb1, acc, 0, 0, 0);
        // C layout: col = lane&15 (key), row = quad*4 + reg (query)
#pragma unroll
        for (int r = 0; r < 4; ++r) {
            const int m = quad * 4 + r;
            const int d = jb - (q0 + m);               // key - query
            const bool in = (d >= -64) && (d <= 64) && (jb < SS);
            evf[m * VST + 40 + 16 * t + m16] = in ? __expf(acc[r]) : 0.f;
        }
    }
    __syncthreads();

    // ---- phase C: virtual-anchor sliding window, all b128-aligned ----
    const int qi = q0 + wq;
    const int s_lo = max(qi - WINR, 0);
    const int s_hi = min(qi + WINR, SS - 1);
    const int a = (s_lo - j0 - 7) & 7;        // virtual head so add-stream is 8-aligned
    const int s_start = s_lo - a;
    const int I_s = s_start - j0 + 8;         // first remove jp; == 7 (mod 8)
    const int I_f = I_s - 7;                  // aligned; init covers [I_f, I_f+72)
    const int A0 = I_f + 72;                  // aligned add-block base (= first add jp)

    const ushort* vrow = Vt + lane * VST;     // this lane's output dim d = lane
    const float*  erow = evf + wq * VST;

    float accA = 0.f, denA = 0.f, accR = 0.f, denR = 0.f;
#pragma unroll
    for (int t = 0; t < 9; ++t) {             // init window(s_start), 7 leading zeros included
        const int base = I_f + 8 * t;
        const uint4v  vv = *(const uint4v*)(vrow + base);
        const float4v e0 = *(const float4v*)(erow + base);
        const float4v e1 = *(const float4v*)(erow + base + 4);
#pragma unroll
        for (int k = 0; k < 8; ++k) {
            const float e = (k < 4) ? e0[k] : e1[k - 4];
            const uint wv = vv[k >> 1];
            const float v = (k & 1) ? bfbits(wv & 0xffff0000u) : bfbits(wv << 16);
            accA = fmaf(e, v, accA);
            denA += e;
        }
    }

    // rolling carry: element 7 of R-block (constant phase offset of the remove stream)
    float pE7 = erow[I_s];
    float pV7 = bf2f(vrow[I_s]);

    int off = offs_of(s_lo);
    float* outb = out + (size_t)b * LTOT * UU;
    const int ng = (s_hi - s_start + 8) >> 3;
    for (int g = 0; g < ng; ++g) {
        const int Ab = A0 + 8 * g;
        const uint4v  Av  = *(const uint4v*)(vrow + Ab);
        const float4v Ae0 = *(const float4v*)(erow + Ab);
        const float4v Ae1 = *(const float4v*)(erow + Ab + 4);
        const int Rb = I_f + 8 * (g + 1);
        const uint4v  Rv  = *(const uint4v*)(vrow + Rb);
        const float4v Re0 = *(const float4v*)(erow + Rb);
        const float4v Re1 = *(const float4v*)(erow + Rb + 4);
        int s = s_start + 8 * g;
#pragma unroll
        for (int k = 0; k < 8; ++k, ++s) {
            if (s >= s_lo && s <= s_hi) {     // wave-uniform predicate (virtual/tail anchors skip)
                const int st = (s - WINR > 0) ? s - WINR : 0;
                const int en = (s + WINR + 1 < SS) ? s + WINR + 1 : SS;
                const float r = __builtin_amdgcn_rcpf(denA - denR);
                outb[(size_t)(off + qi - st) * UU + lane] = (accA - accR) * r;
                off += en - st;
            }
            {   // add key s+33 (element k of A block; e=0 past band/seq-end)
                const float e = (k < 4) ? Ae0[k] : Ae1[k - 4];
                const uint wv = Av[k >> 1];
                const float v = (k & 1) ? bfbits(wv & 0xffff0000u) : bfbits(wv << 16);
                accA = fmaf(e, v, accA);
                denA += e;
            }
            {   // remove key s-32 (k==0 -> carried elem 7 of prev R block, else new block k-1)
                float e, v;
                if (k == 0) { e = pE7; v = pV7; }
                else {
                    const int m = k - 1;
                    e = (m < 4) ? Re0[m] : Re1[m - 4];
                    const uint wv = Rv[m >> 1];
                    v = (m & 1) ? bfbits(wv & 0xffff0000u) : bfbits(wv << 16);
                }
                accR = fmaf(e, v, accR);
                denR += e;
            }
        }
        pE7 = Re1[3];
        pV7 = bfbits(Rv[3] & 0xffff0000u);
    }
}

extern "C" void kernel_launch(void* const* d_in, const int* in_sizes, int n_in,
                              void* d_out, int out_size, void* d_ws, size_t ws_size,
                              hipStream_t stream) {
    const float* query = (const float*)d_in[0];
    const float* value = (const float*)d_in[1];
    const float* Wq = (const float*)d_in[2];
    const float* bq = (const float*)d_in[3];
    const float* Wk = (const float*)d_in[4];
    const float* bk = (const float*)d_in[5];
    const float* Wv = (const float*)d_in[6];
    const float* bv = (const float*)d_in[7];
    float* out = (float*)d_out;

    // ws: Qs fp32 (2 MB) + Kf bf16 (1 MB) + Vf bf16 (1 MB)
    float* Qs = (float*)d_ws;
    ushort* Kf = (ushort*)(Qs + (size_t)BB * SS * UU);
    ushort* Vf = Kf + (size_t)BB * SS * UU;
    // Wt (bf16 [3][64][512], 192 KB) in the TAIL of d_out: prep_w writes, qkv_mfma reads,
    // attn_kernel then overwrites every output row (stream-ordered, 16B-aligned).
    ushort* Wt = (ushort*)((float*)d_out + (size_t)out_size) - (size_t)3 * UU * DIN;

    prep_w<<<24, 256, 0, stream>>>(Wq, Wk, Wv, Wt);
    qkv_mfma<<<3 * 512, 256, 0, stream>>>(query, value, Wt, bq, bk, bv, Qs, Kf, Vf);
    attn_kernel<<<512, 1024, 0, stream>>>(Qs, Kf, Vf, out);
}

// Round 3
// 198.608 us; speedup vs baseline: 1.0846x; 1.0002x over previous
//
#include <hip/hip_runtime.h>
#include <hip/hip_bf16.h>

#define BB 4
#define SS 2048
#define DIN 512
#define UU 64
#define WINR 32
#define LTOT 132064   // sum of per-anchor window lengths
#define GQ 16         // queries per attn block (16 waves x 1 query)
#define VST 200       // padded key-dim stride: 40 left-pad + 144 band + 16 right pad
#define RST 65        // red-buffer row stride (floats): kills 16-way bank conflict in V epilogue

typedef __attribute__((ext_vector_type(8))) short short8;
typedef __attribute__((ext_vector_type(4))) float float4v;
typedef __attribute__((ext_vector_type(4))) uint uint4v;

static __device__ __forceinline__ ushort f2bf(float f) {
    union { __hip_bfloat16 h; ushort u; } c;
    c.h = __float2bfloat16(f);
    return c.u;
}
static __device__ __forceinline__ float bf2f(ushort u) {
    union { float f; uint v; } c;
    c.v = ((uint)u) << 16;
    return c.f;
}
static __device__ __forceinline__ float bfbits(uint u) {   // float from raw bits
    union { float f; uint v; } c;
    c.v = u;
    return c.f;
}

// offsets[s] = sum_{t<s} (min(t+33,S) - max(t-32,0)), closed form (verified vs cumsum)
__device__ __forceinline__ int offs_of(int s) {
    int a = s < (SS - 33) ? s : (SS - 33);
    int m = (s - 33) > 0 ? (s - 33) : 0;
    return a * (a - 1) / 2 + 33 * a + (s - a) * SS - m * (m + 1) / 2;
}

// ---------------- Kernel 0: W (fp32, K-major [512][64]) -> Wt (bf16, N-major [3][64][512]) ----
__global__ __launch_bounds__(256) void prep_w(
    const float* __restrict__ Wq, const float* __restrict__ Wk, const float* __restrict__ Wv,
    ushort* __restrict__ Wt)
{
    __shared__ float T[64][65];
    const int mtx = blockIdx.x >> 3;   // 0..2
    const int kc  = blockIdx.x & 7;    // 0..7  (K chunk of 64)
    const float* W = (mtx == 0) ? Wq : ((mtx == 1) ? Wk : Wv);
    const int tid = threadIdx.x;
    for (int idx = tid; idx < 64 * 64; idx += 256) {
        const int k = idx >> 6, n = idx & 63;          // coalesced read over n
        T[n][k] = W[(size_t)(kc * 64 + k) * UU + n];
    }
    __syncthreads();
    for (int idx = tid; idx < 64 * 64; idx += 256) {
        const int n = idx >> 6, kl = idx & 63;
        Wt[(size_t)mtx * UU * DIN + (size_t)n * DIN + kc * 64 + kl] = f2bf(T[n][kl]);
    }
}

// ---------------- Kernel 1: fused QKV projection (v4) ----------------
// grid = 1024 blocks x 256 threads.
//   bid < 512 : Q tile rt=bid       (reads query, Wt[0], writes Qs fp32 row-major, pre-scaled)
//   bid >= 512: K+V tile rt=bid-512 (reads value ONCE, Wt[1]+Wt[2], shared A-fragments,
//               writes Kf bf16 row-major and V bf16 TRANSPOSED Vtg[b][d][j] for cheap attn staging)
// red stride RST=65 removes bank conflicts in both epilogue read patterns.
__global__ __launch_bounds__(256) void qkv_mfma(
    const float* __restrict__ query, const float* __restrict__ value,
    const ushort* __restrict__ Wt,
    const float* __restrict__ bq, const float* __restrict__ bk, const float* __restrict__ bv,
    float* __restrict__ Qs, ushort* __restrict__ Kf, ushort* __restrict__ Vtg)
{
    __shared__ float red[4][16 * RST];   // 16.6 KB partials
    const int bid = blockIdx.x;
    const bool isQ = bid < 512;
    const int rt  = isQ ? bid : bid - 512;
    const int tid = threadIdx.x;
    const int kq = tid >> 6;            // K-quarter
    const int lane = tid & 63;
    const int m16 = lane & 15, quad = lane >> 4;

    const float* X = isQ ? query : value;
    const float* Xrow = X + (size_t)(rt * 16 + m16) * DIN + kq * 128 + quad * 8;
    // Q uses Wt[0]; KV block: K weights at Wt[1], V weights at Wt[2] (= +UU*DIN from K)
    const ushort* Wm = Wt + (size_t)(isQ ? 0 : 1) * UU * DIN
                          + (size_t)m16 * DIN + kq * 128 + quad * 8;

    float4v acc0[4], acc1[4];
#pragma unroll
    for (int nb = 0; nb < 4; ++nb) {
        acc0[nb] = (float4v){0.f, 0.f, 0.f, 0.f};
        acc1[nb] = (float4v){0.f, 0.f, 0.f, 0.f};
    }

#pragma unroll
    for (int kk = 0; kk < 4; ++kk) {
        const float4 xa = *(const float4*)(Xrow + kk * 32);
        const float4 xb = *(const float4*)(Xrow + kk * 32 + 4);
        short8 a;
        a[0] = (short)f2bf(xa.x); a[1] = (short)f2bf(xa.y);
        a[2] = (short)f2bf(xa.z); a[3] = (short)f2bf(xa.w);
        a[4] = (short)f2bf(xb.x); a[5] = (short)f2bf(xb.y);
        a[6] = (short)f2bf(xb.z); a[7] = (short)f2bf(xb.w);
#pragma unroll
        for (int nb = 0; nb < 4; ++nb) {
            const short8 b0 = *(const short8*)(Wm + (size_t)nb * 16 * DIN + kk * 32);
            acc0[nb] = __builtin_amdgcn_mfma_f32_16x16x32_bf16(a, b0, acc0[nb], 0, 0, 0);
        }
        if (!isQ) {
#pragma unroll
            for (int nb = 0; nb < 4; ++nb) {
                const short8 b1 = *(const short8*)(Wm + (size_t)UU * DIN + (size_t)nb * 16 * DIN + kk * 32);
                acc1[nb] = __builtin_amdgcn_mfma_f32_16x16x32_bf16(a, b1, acc1[nb], 0, 0, 0);
            }
        }
    }

    // ---- pass 1: Q or K, row-major output ----
    // C layout (16x16x32): col = lane&15 (within nb tile), row = quad*4 + reg
#pragma unroll
    for (int nb = 0; nb < 4; ++nb)
#pragma unroll
        for (int reg = 0; reg < 4; ++reg)
            red[kq][(quad * 4 + reg) * RST + nb * 16 + m16] = acc0[nb][reg];
    __syncthreads();

    const float* bias0 = isQ ? bq : bk;
#pragma unroll
    for (int i = 0; i < 4; ++i) {
        const int e = tid + 256 * i;
        const int col = e & 63, row = e >> 6;
        const int ra = row * RST + col;
        float s = red[0][ra] + red[1][ra] + red[2][ra] + red[3][ra] + bias0[col];
        const size_t gi = (size_t)(rt * 16 + row) * UU + col;
        if (isQ) Qs[gi] = s * 0.125f;    // 1/sqrt(UNITS)
        else     Kf[gi] = f2bf(s);
    }
    if (isQ) return;

    // ---- pass 2: V, transposed output Vtg[b][d][j] ----
    __syncthreads();
#pragma unroll
    for (int nb = 0; nb < 4; ++nb)
#pragma unroll
        for (int reg = 0; reg < 4; ++reg)
            red[kq][(quad * 4 + reg) * RST + nb * 16 + m16] = acc1[nb][reg];
    __syncthreads();
#pragma unroll
    for (int i = 0; i < 4; ++i) {
        const int e = tid + 256 * i;
        const int row = e & 15, col = e >> 4;      // consecutive threads -> consecutive j
        const int ra = row * RST + col;
        const float s = red[0][ra] + red[1][ra] + red[2][ra] + red[3][ra] + bv[col];
        const int r = rt * 16 + row;               // global row in [0, 8192)
        const int bb = r >> 11, j = r & 2047;
        Vtg[(((size_t)(bb * UU + col)) << 11) + j] = f2bf(s);
    }
}

// ---------------- Kernel 2: MFMA scores + b128 sliding-window sums (v4) ----------
// 512 blocks x 1024 thr (16 waves); wave w = query q0+w in phase C.
// v4 changes: V staged from the TRANSPOSED Vtg via b128 global loads + b128 LDS writes
// (was: uncoalesced uint loads + 8-way-conflicted ds_write_u16); interior blocks (120/128)
// run a predicate-free phase-C main loop with constant window 65 and pointer-increment stores.
__global__ __launch_bounds__(1024, 8) void attn_kernel(
    const float* __restrict__ Qs, const ushort* __restrict__ Kf,
    const ushort* __restrict__ Vtg, float* __restrict__ out)
{
    __shared__ __align__(16) ushort Vt[UU * VST];      // 25,600 B  Vt[d][jp], jp = j - j0 + 40
    __shared__ __align__(16) float  evf[GQ * VST];     // 12,800 B  exp-scores per query

    const int blk = blockIdx.x;
    const int b = blk >> 7;              // 128 blocks per batch
    const int q0 = (blk & 127) << 4;
    const int tid = threadIdx.x;
    const int lane = tid & 63;
    const int wq = __builtin_amdgcn_readfirstlane(tid >> 6);   // provably wave-uniform

    const int j0 = max(q0 - 2 * WINR, 0);
    const int j1 = min(q0 + GQ - 1 + 2 * WINR + 1, SS);
    const int nw = j1 - j0;              // always a multiple of 16

    // ---- zero Vt (pads must be 0.0: 0*NaN would poison acc) and all of evf, b128 stores ----
    {
        const uint4v z = (uint4v){0u, 0u, 0u, 0u};
        uint4v* V4 = (uint4v*)Vt;                      // 1600 vectors
        uint4v* E4 = (uint4v*)evf;                     //  800 vectors
        for (int i = tid; i < 1600; i += 1024) V4[i] = z;
        for (int i = tid; i < 800;  i += 1024) E4[i] = z;
    }
    __syncthreads();

    if (wq >= 9) {
        // ---- waves 9..15: stage V from transposed Vtg, 16B granularity both sides ----
        const ushort* Vsrc = Vtg + ((size_t)b << 17);          // [64][2048] rows for this batch
        for (int idx = tid - 9 * 64; idx < UU * 18; idx += 7 * 64) {
            const int d = idx / 18, t = idx - d * 18;          // chunk t of row d
            if (t * 8 < nw) {
                const uint4v v = *(const uint4v*)(Vsrc + ((size_t)d << 11) + j0 + t * 8);
                *(uint4v*)(Vt + d * VST + 40 + t * 8) = v;
            }
        }
    } else {
        // ---- waves 0..8: score tile t = wq -> evf rows [0,16), cols [40+16t, 40+16t+16) ----
        const int t = wq;
        const int m16 = lane & 15, quad = lane >> 4;
        const int jb = j0 + 16 * t + m16;              // this lane's key index (unclamped)
        const int jr = jb < SS ? jb : SS - 1;          // clamped for the load
        const ushort* kr = Kf + ((size_t)b * SS + jr) * UU + quad * 8;
        const float*  qr = Qs + ((size_t)b * SS + q0 + m16) * UU + quad * 8;
        const short8 kb0 = *(const short8*)(kr);         // k in [quad*8, quad*8+8)
        const short8 kb1 = *(const short8*)(kr + 32);    // k + 32
        short8 ah0, al0, ah1, al1;                       // Q hi/lo bf16 split
#pragma unroll
        for (int e = 0; e < 8; ++e) {
            const float qa = qr[e], qb = qr[e + 32];
            const ushort h0 = f2bf(qa);
            ah0[e] = (short)h0; al0[e] = (short)f2bf(qa - bf2f(h0));
            const ushort h1 = f2bf(qb);
            ah1[e] = (short)h1; al1[e] = (short)f2bf(qb - bf2f(h1));
        }
        float4v acc = (float4v){0.f, 0.f, 0.f, 0.f};
        acc = __builtin_amdgcn_mfma_f32_16x16x32_bf16(ah0, kb0, acc, 0, 0, 0);
        acc = __builtin_amdgcn_mfma_f32_16x16x32_bf16(al0, kb0, acc, 0, 0, 0);
        acc = __builtin_amdgcn_mfma_f32_16x16x32_bf16(ah1, kb1, acc, 0, 0, 0);
        acc = __builtin_amdgcn_mfma_f32_16x16x32_bf16(al1, kb1, acc, 0, 0, 0);
        // C layout: col = lane&15 (key), row = quad*4 + reg (query)
#pragma unroll
        for (int r = 0; r < 4; ++r) {
            const int m = quad * 4 + r;
            const int d = jb - (q0 + m);               // key - query
            const bool in = (d >= -64) && (d <= 64) && (jb < SS);
            evf[m * VST + 40 + 16 * t + m16] = in ? __expf(acc[r]) : 0.f;
        }
    }
    __syncthreads();

    // ---- phase C: virtual-anchor sliding window, all b128-aligned ----
    const int qi = q0 + wq;
    const int s_lo = max(qi - WINR, 0);
    const int s_hi = min(qi + WINR, SS - 1);
    const int a = (s_lo - j0 - 7) & 7;        // virtual head so add-stream is 8-aligned
    const int s_start = s_lo - a;
    const int I_s = s_start - j0 + 8;         // first remove jp; == 7 (mod 8)
    const int I_f = I_s - 7;                  // aligned; init covers [I_f, I_f+72)
    const int A0 = I_f + 72;                  // aligned add-block base (= first add jp)

    const ushort* vrow = Vt + lane * VST;     // this lane's output dim d = lane
    const float*  erow = evf + wq * VST;

    float accA = 0.f, denA = 0.f, accR = 0.f, denR = 0.f;
#pragma unroll
    for (int t = 0; t < 9; ++t) {             // init window(s_start), 7 leading zeros included
        const int base = I_f + 8 * t;
        const uint4v  vv = *(const uint4v*)(vrow + base);
        const float4v e0 = *(const float4v*)(erow + base);
        const float4v e1 = *(const float4v*)(erow + base + 4);
#pragma unroll
        for (int k = 0; k < 8; ++k) {
            const float e = (k < 4) ? e0[k] : e1[k - 4];
            const uint wv = vv[k >> 1];
            const float v = (k & 1) ? bfbits(wv & 0xffff0000u) : bfbits(wv << 16);
            accA = fmaf(e, v, accA);
            denA += e;
        }
    }

    // rolling carry: element 7 of R-block (constant phase offset of the remove stream)
    float pE7 = erow[I_s];
    float pV7 = bf2f(vrow[I_s]);

    float* outb = out + (size_t)b * LTOT * UU;

    if (q0 >= 64 && q0 <= SS - 80) {
        // ======== interior fast path: all 16 queries unclamped, window length 65 ========
        // first real anchor s_lo stores at row offs_of(s_lo)+64; each next real anchor +64 rows
        float* pst = outb + ((size_t)offs_of(s_lo) + 64) * UU + lane;
        for (int g = 0; g < 9; ++g) {
            const int Ab = A0 + 8 * g;
            const uint4v  Av  = *(const uint4v*)(vrow + Ab);
            const float4v Ae0 = *(const float4v*)(erow + Ab);
            const float4v Ae1 = *(const float4v*)(erow + Ab + 4);
            const int Rb = I_f + 8 * (g + 1);
            const uint4v  Rv  = *(const uint4v*)(vrow + Rb);
            const float4v Re0 = *(const float4v*)(erow + Rb);
            const float4v Re1 = *(const float4v*)(erow + Rb + 4);
#pragma unroll
            for (int k = 0; k < 8; ++k) {
                const bool real = (g == 0) ? (k >= a) : ((g < 8) ? true : (k <= a));
                if (real) {   // wave-uniform
                    const float r = __builtin_amdgcn_rcpf(denA - denR);
                    *pst = (accA - accR) * r;
                    pst += (size_t)64 * UU;
                }
                {   // add
                    const float e = (k < 4) ? Ae0[k] : Ae1[k - 4];
                    const uint wv = Av[k >> 1];
                    const float v = (k & 1) ? bfbits(wv & 0xffff0000u) : bfbits(wv << 16);
                    accA = fmaf(e, v, accA);
                    denA += e;
                }
                {   // remove
                    float e, v;
                    if (k == 0) { e = pE7; v = pV7; }
                    else {
                        const int m = k - 1;
                        e = (m < 4) ? Re0[m] : Re1[m - 4];
                        const uint wv = Rv[m >> 1];
                        v = (m & 1) ? bfbits(wv & 0xffff0000u) : bfbits(wv << 16);
                    }
                    accR = fmaf(e, v, accR);
                    denR += e;
                }
            }
            pE7 = Re1[3];
            pV7 = bfbits(Rv[3] & 0xffff0000u);
        }
    } else {
        // ======== generic path (edge blocks, 8/128): round-2 verbatim ========
        int off = offs_of(s_lo);
        const int ng = (s_hi - s_start + 8) >> 3;
        for (int g = 0; g < ng; ++g) {
            const int Ab = A0 + 8 * g;
            const uint4v  Av  = *(const uint4v*)(vrow + Ab);
            const float4v Ae0 = *(const float4v*)(erow + Ab);
            const float4v Ae1 = *(const float4v*)(erow + Ab + 4);
            const int Rb = I_f + 8 * (g + 1);
            const uint4v  Rv  = *(const uint4v*)(vrow + Rb);
            const float4v Re0 = *(const float4v*)(erow + Rb);
            const float4v Re1 = *(const float4v*)(erow + Rb + 4);
            int s = s_start + 8 * g;
#pragma unroll
            for (int k = 0; k < 8; ++k, ++s) {
                if (s >= s_lo && s <= s_hi) {     // wave-uniform predicate
                    const int st = (s - WINR > 0) ? s - WINR : 0;
                    const int en = (s + WINR + 1 < SS) ? s + WINR + 1 : SS;
                    const float r = __builtin_amdgcn_rcpf(denA - denR);
                    outb[(size_t)(off + qi - st) * UU + lane] = (accA - accR) * r;
                    off += en - st;
                }
                {   // add key s+33
                    const float e = (k < 4) ? Ae0[k] : Ae1[k - 4];
                    const uint wv = Av[k >> 1];
                    const float v = (k & 1) ? bfbits(wv & 0xffff0000u) : bfbits(wv << 16);
                    accA = fmaf(e, v, accA);
                    denA += e;
                }
                {   // remove key s-32
                    float e, v;
                    if (k == 0) { e = pE7; v = pV7; }
                    else {
                        const int m = k - 1;
                        e = (m < 4) ? Re0[m] : Re1[m - 4];
                        const uint wv = Rv[m >> 1];
                        v = (m & 1) ? bfbits(wv & 0xffff0000u) : bfbits(wv << 16);
                    }
                    accR = fmaf(e, v, accR);
                    denR += e;
                }
            }
            pE7 = Re1[3];
            pV7 = bfbits(Rv[3] & 0xffff0000u);
        }
    }
}

extern "C" void kernel_launch(void* const* d_in, const int* in_sizes, int n_in,
                              void* d_out, int out_size, void* d_ws, size_t ws_size,
                              hipStream_t stream) {
    const float* query = (const float*)d_in[0];
    const float* value = (const float*)d_in[1];
    const float* Wq = (const float*)d_in[2];
    const float* bq = (const float*)d_in[3];
    const float* Wk = (const float*)d_in[4];
    const float* bk = (const float*)d_in[5];
    const float* Wv = (const float*)d_in[6];
    const float* bv = (const float*)d_in[7];
    float* out = (float*)d_out;

    // ws: Qs fp32 (2 MB) + Kf bf16 (1 MB) + Vtg bf16 transposed [B][64][2048] (1 MB)
    float* Qs = (float*)d_ws;
    ushort* Kf = (ushort*)(Qs + (size_t)BB * SS * UU);
    ushort* Vtg = Kf + (size_t)BB * SS * UU;
    // Wt (bf16 [3][64][512], 192 KB) in the TAIL of d_out: prep_w writes, qkv_mfma reads,
    // attn_kernel then overwrites every output row (stream-ordered, 16B-aligned).
    ushort* Wt = (ushort*)((float*)d_out + (size_t)out_size) - (size_t)3 * UU * DIN;

    prep_w<<<24, 256, 0, stream>>>(Wq, Wk, Wv, Wt);
    qkv_mfma<<<1024, 256, 0, stream>>>(query, value, Wt, bq, bk, bv, Qs, Kf, Vtg);
    attn_kernel<<<512, 1024, 0, stream>>>(Qs, Kf, Vtg, out);
}